// Round 13
// baseline (97.534 us; speedup 1.0000x reference)
//
#include <hip/hip_runtime.h>
#include <hip/hip_bf16.h>
#include <stdint.h>

// Shapes (fixed): S=4, B=2, F=64, P=16, T=32, H=64, W=64, HID=32
#define THW   131072   // 32*64*64
#define NS    4
#define NB    2
#define NF    64
#define NP    16
#define HID   32
#define BN_EPS 1e-5f
#define PXT   64       // pixels per block tile (2 waves x 32-px MFMA tiles)

typedef short  bf16x8  __attribute__((ext_vector_type(8)));
typedef float  f32x16  __attribute__((ext_vector_type(16)));

union FragU { uint32_t u[4]; bf16x8 v; uint4 q; };

__device__ __forceinline__ uint32_t pk2(float a, float b) {
    __hip_bfloat162 h = __float22bfloat162_rn(make_float2(a, b));
    uint32_t r;
    __builtin_memcpy(&r, &h, sizeof(r));
    return r;
}
__device__ __forceinline__ float lo16(uint32_t u) { return __builtin_bit_cast(float, u << 16); }
__device__ __forceinline__ float hi16(uint32_t u) { return __builtin_bit_cast(float, u & 0xFFFF0000u); }

__device__ __forceinline__ void glds16(const float* g, void* l) {
    __builtin_amdgcn_global_load_lds(
        (const __attribute__((address_space(1))) uint32_t*)g,
        (__attribute__((address_space(3))) uint32_t*)l, 16, 0, 0);
}

// R13: stage ALL data up front (34 DMA instrs/wave = p + 4 s-tiles), then a
// pure counted-vmcnt ladder 24/16/8/0 — one issue burst, zero re-staging,
// per-wave ~34KB in flight (4x R10's depth). 128-thr blocks (2 waves),
// PXT=64, LDS 75.5KB -> 2 blocks/CU. brev12 swizzle (R10: +10%).
// Ladder correctness: w1/tbl global loads complete BEFORE the DMA burst
// (compiler-inserted waits at their use), so outstanding DMAs = exactly 34.
__global__ __launch_bounds__(128, 2) void gssm_kernel(
    const float* __restrict__ feats, const float* __restrict__ ps,
    const float* __restrict__ w1,    const float* __restrict__ gamma,
    const float* __restrict__ beta,  const float* __restrict__ mean,
    const float* __restrict__ var,   const float* __restrict__ w2,
    float* __restrict__ out)
{
    __shared__ __align__(16) float    fbuf[NS][NF][PXT];   // 65536 B
    __shared__ __align__(16) float    pbuf[NP][PXT];       //  4096 B
    __shared__ __align__(16) uint32_t w1lds[32 * 44];      //  5632 B
    __shared__ float2 tbl[HID];                            //   256 B

    const int tid  = threadIdx.x;
    const int lane = tid & 63;
    const int wv   = tid >> 6;      // 0..1
    const int hi   = lane >> 5;
    const int ln   = lane & 31;

    // ---- stage w1 (BN-scale folded, bf16-packed) + tbl; these global loads
    // must RETIRE before the DMA burst so the vmcnt ladder counts are exact.
    for (int t = tid; t < 1280; t += 128) {
        float2 v = ((const float2*)w1)[t];
        int o = t / 40, cp = t - o * 40;
        float sc = gamma[o] * rsqrtf(var[o] + BN_EPS);
        w1lds[o * 44 + (cp >> 3) * 8 + (cp & 7)] = pk2(v.x * sc, v.y * sc);
    }
    if (tid < HID) {
        float sc = gamma[tid] * rsqrtf(var[tid] + BN_EPS);
        tbl[tid] = make_float2(beta[tid] - mean[tid] * sc, w2[tid]);
    }
    asm volatile("s_waitcnt vmcnt(0)" ::: "memory");   // drain w1/tbl loads

    const int tile = (int)(__brev((unsigned)blockIdx.x) >> 20);  // 12-bit bitrev, 4096 tiles
    const int px0g = tile * PXT;
    const int b    = px0g >> 17;               // THW = 2^17
    const int px0  = px0g & (THW - 1);

    const float* featsb = feats + (long)b * NF * THW + px0;
    const float* psb    = ps    + (long)b * NP * THW + px0;
    const long   sstr   = (long)NB * NF * THW;

    // One glds16 = 1KB = 4 planes x 256B (16 lanes per plane, 16B/lane).
    const long lsub = (long)(lane >> 4) * THW + (long)(lane & 15) * 4;

    // ---- THE BURST: 34 DMA instrs per wave (2 p + 4s x 8 feats)
    #pragma unroll
    for (int j = 0; j < 2; ++j) {
        const int p4 = wv * 8 + j * 4;
        glds16(psb + (long)p4 * THW + lsub, (void*)&pbuf[p4][0]);
    }
    #pragma unroll
    for (int s = 0; s < NS; ++s) {
        const float* base = featsb + (long)s * sstr;
        #pragma unroll
        for (int i = 0; i < 8; ++i) {
            const int f4 = wv * 32 + i * 4;
            glds16(base + (long)f4 * THW + lsub, (void*)&fbuf[s][f4][0]);
        }
    }

    // ---- make w1lds/tbl visible; DMAs stay in flight
    asm volatile("s_waitcnt lgkmcnt(0)" ::: "memory");
    __builtin_amdgcn_s_barrier();

    // ---- hoist A fragments (w1*scale) and shift/w2 (per-lane)
    FragU afr[5];
    {
        const uint32_t abase = (uint32_t)(ln * 44 + hi * 4);
        #pragma unroll
        for (int k = 0; k < 5; ++k)
            afr[k].q = *((const uint4*)&w1lds[abase + k * 8]);
    }
    float sh[16], wo[16];
    #pragma unroll
    for (int r = 0; r < 16; ++r) {
        float2 t = tbl[(r & 3) + 8 * (r >> 2) + 4 * hi];
        sh[r] = t.x;
        wo[r] = t.y;
    }

    const int pxloc = wv * 32 + ln;

    FragU bp;   // packed after ladder step 0 (p arrives with s0)

    auto consume = [&](int s, FragU* pk) -> float {
        #pragma unroll
        for (int kb = 0; kb < 4; ++kb)
            #pragma unroll
            for (int r = 0; r < 4; ++r)
                pk[kb].u[r] = pk2(fbuf[s][kb * 16 + hi * 8 + 2 * r][pxloc],
                                  fbuf[s][kb * 16 + hi * 8 + 2 * r + 1][pxloc]);
        f32x16 acc;
        #pragma unroll
        for (int r = 0; r < 16; ++r) acc[r] = 0.f;
        acc = __builtin_amdgcn_mfma_f32_32x32x16_bf16(afr[4].v, bp.v,    acc, 0, 0, 0);
        acc = __builtin_amdgcn_mfma_f32_32x32x16_bf16(afr[0].v, pk[0].v, acc, 0, 0, 0);
        acc = __builtin_amdgcn_mfma_f32_32x32x16_bf16(afr[1].v, pk[1].v, acc, 0, 0, 0);
        acc = __builtin_amdgcn_mfma_f32_32x32x16_bf16(afr[2].v, pk[2].v, acc, 0, 0, 0);
        acc = __builtin_amdgcn_mfma_f32_32x32x16_bf16(afr[3].v, pk[3].v, acc, 0, 0, 0);
        float pp4[4] = {0.f, 0.f, 0.f, 0.f};
        #pragma unroll
        for (int r = 0; r < 16; ++r) {
            float h = fmaxf(acc[r] + sh[r], 0.f);
            pp4[r & 3] = fmaf(h, wo[r], pp4[r & 3]);
        }
        float part = (pp4[0] + pp4[1]) + (pp4[2] + pp4[3]);
        return part + __shfl_xor(part, 32);
    };

    FragU pk0[4], pk1[4], pk2f[4], pk3[4];
    float lg0, lg1, lg2, lg3;

    // ---- counted-vmcnt ladder: p+s0 done at 24; s1 at 16; s2 at 8; s3 at 0.
    asm volatile("s_waitcnt vmcnt(24)" ::: "memory");
    __builtin_amdgcn_s_barrier();
    #pragma unroll
    for (int r = 0; r < 4; ++r)
        bp.u[r] = pk2(pbuf[hi * 8 + 2 * r][pxloc], pbuf[hi * 8 + 2 * r + 1][pxloc]);
    lg0 = consume(0, pk0);

    asm volatile("s_waitcnt vmcnt(16)" ::: "memory");
    __builtin_amdgcn_s_barrier();
    lg1 = consume(1, pk1);

    asm volatile("s_waitcnt vmcnt(8)" ::: "memory");
    __builtin_amdgcn_s_barrier();
    lg2 = consume(2, pk2f);

    asm volatile("s_waitcnt vmcnt(0)" ::: "memory");
    __builtin_amdgcn_s_barrier();
    lg3 = consume(3, pk3);

    // ---- softmax over 4 logits (b2 shift-invariant: skipped)
    const float m   = fmaxf(fmaxf(lg0, lg1), fmaxf(lg2, lg3));
    const float e0  = __expf(lg0 - m), e1 = __expf(lg1 - m);
    const float e2  = __expf(lg2 - m), e3 = __expf(lg3 - m);
    const float inv = 1.f / (e0 + e1 + e2 + e3);
    const float a0 = e0 * inv, a1 = e1 * inv, a2 = e2 * inv, a3 = e3 * inv;

    const int thw = px0 + pxloc;

    // ---- out[b][f][thw] = sum_s alpha_s * feats_s (from bf16 frags), f = k*16+hi*8+j
    float* ob = out + ((long)(b * NF + hi * 8)) * THW + thw;
    #pragma unroll
    for (int k = 0; k < 4; ++k)
        #pragma unroll
        for (int r = 0; r < 4; ++r) {
            float vlo = a0 * lo16(pk0[k].u[r]);
            float vhi = a0 * hi16(pk0[k].u[r]);
            vlo = fmaf(a1, lo16(pk1[k].u[r]), vlo);
            vhi = fmaf(a1, hi16(pk1[k].u[r]), vhi);
            vlo = fmaf(a2, lo16(pk2f[k].u[r]), vlo);
            vhi = fmaf(a2, hi16(pk2f[k].u[r]), vhi);
            vlo = fmaf(a3, lo16(pk3[k].u[r]), vlo);
            vhi = fmaf(a3, hi16(pk3[k].u[r]), vhi);
            ob[(long)(k * 16 + 2 * r)     * THW] = vlo;
            ob[(long)(k * 16 + 2 * r + 1) * THW] = vhi;
        }

    // ---- alpha[b][s][thw] at offset B*F*THW; hi=0 -> s=0,1 ; hi=1 -> s=2,3
    float* ab = out + (long)NB * NF * THW + ((long)(b * NS + hi * 2)) * THW + thw;
    ab[0]   = hi ? a2 : a0;
    ab[THW] = hi ? a3 : a1;
}

extern "C" void kernel_launch(void* const* d_in, const int* in_sizes, int n_in,
                              void* d_out, int out_size, void* d_ws, size_t ws_size,
                              hipStream_t stream) {
    const float* feats = (const float*)d_in[0];
    const float* ps    = (const float*)d_in[1];
    const float* w1    = (const float*)d_in[2];
    const float* gamma = (const float*)d_in[3];
    const float* beta  = (const float*)d_in[4];
    const float* mean  = (const float*)d_in[5];
    const float* var   = (const float*)d_in[6];
    const float* w2    = (const float*)d_in[7];
    float* out = (float*)d_out;

    dim3 grid(4096), block(128);   // 4096 blocks x 64 px = 262144 pixels
    hipLaunchKernelGGL(gssm_kernel, grid, block, 0, stream,
                       feats, ps, w1, gamma, beta, mean, var, w2, out);
}

// Round 14
// 80.105 us; speedup vs baseline: 1.2176x; 1.2176x over previous
//
#include <hip/hip_runtime.h>
#include <hip/hip_bf16.h>
#include <stdint.h>

// Shapes (fixed): S=4, B=2, F=64, P=16, T=32, H=64, W=64, HID=32
#define THW   131072   // 32*64*64
#define NS    4
#define NB    2
#define NF    64
#define NP    16
#define HID   32
#define BN_EPS 1e-5f
#define PXT   128      // pixels per block tile (4 waves x 32-px MFMA tiles)
#define TPB   4        // tiles per persistent block

typedef short  bf16x8  __attribute__((ext_vector_type(8)));
typedef float  f32x16  __attribute__((ext_vector_type(16)));

union FragU { uint32_t u[4]; bf16x8 v; uint4 q; };

__device__ __forceinline__ uint32_t pk2(float a, float b) {
    __hip_bfloat162 h = __float22bfloat162_rn(make_float2(a, b));
    uint32_t r;
    __builtin_memcpy(&r, &h, sizeof(r));
    return r;
}
__device__ __forceinline__ float lo16(uint32_t u) { return __builtin_bit_cast(float, u << 16); }
__device__ __forceinline__ float hi16(uint32_t u) { return __builtin_bit_cast(float, u & 0xFFFF0000u); }

__device__ __forceinline__ void glds16(const float* g, void* l) {
    __builtin_amdgcn_global_load_lds(
        (const __attribute__((address_space(1))) uint32_t*)g,
        (__attribute__((address_space(3))) uint32_t*)l, 16, 0, 0);
}

// R14 = R10's schedule made PERSISTENT: 512 blocks (2/CU), each rolls the
// counted-vmcnt phase pipeline across 4 tiles with no per-tile fill/drain.
// Tile map: tile(bid,t) = 4*brev9(bid) + t -> resident cohort at any t-slice
// = {4k+t}, stride-4 full-span (same channel spread as R10's brev11, +10%).
// Per phase: stage(next) -> vmcnt(count of just-issued) -> barrier ->
// consume -> barrier. p for tile t+1 staged with s=3's phase (10 DMAs).
__global__ __launch_bounds__(256, 2) void gssm_kernel(
    const float* __restrict__ feats, const float* __restrict__ ps,
    const float* __restrict__ w1,    const float* __restrict__ gamma,
    const float* __restrict__ beta,  const float* __restrict__ mean,
    const float* __restrict__ var,   const float* __restrict__ w2,
    float* __restrict__ out)
{
    __shared__ __align__(16) float    fbuf[2][NF][PXT];   // 65536 B
    __shared__ __align__(16) float    pbuf[NP][PXT];      //  8192 B
    __shared__ __align__(16) uint32_t w1lds[32 * 44];     //  5632 B
    __shared__ float2 tbl[HID];                           //   256 B

    const int tid  = threadIdx.x;
    const int lane = tid & 63;
    const int wv   = tid >> 6;      // 0..3
    const int hi   = lane >> 5;
    const int ln   = lane & 31;

    // ---- stage w1 (BN-scale folded, bf16-packed) + tbl; drain these vmem
    // loads so the DMA vmcnt ladder counts stay exact.
    for (int t = tid; t < 1280; t += 256) {
        float2 v = ((const float2*)w1)[t];
        int o = t / 40, cp = t - o * 40;
        float sc = gamma[o] * rsqrtf(var[o] + BN_EPS);
        w1lds[o * 44 + (cp >> 3) * 8 + (cp & 7)] = pk2(v.x * sc, v.y * sc);
    }
    if (tid < HID) {
        float sc = gamma[tid] * rsqrtf(var[tid] + BN_EPS);
        tbl[tid] = make_float2(beta[tid] - mean[tid] * sc, w2[tid]);
    }
    asm volatile("s_waitcnt vmcnt(0)" ::: "memory");

    const int base9 = (int)(__brev((unsigned)blockIdx.x) >> 23);  // 9-bit bitrev
    const long sstr = (long)NB * NF * THW;
    const long pl_off = (long)(lane >> 5) * THW + (ln << 2);
    const int  f0     = wv * 16;

    // per-tile geometry
    auto tile_b   = [&](int t) { return (4 * base9 + t) >> 10; };          // tile/1024
    auto tile_px0 = [&](int t) { return ((4 * base9 + t) * PXT) & (THW - 1); };

    auto stage_feats = [&](int t, int s, int buf) {
        const float* base = feats + (long)tile_b(t) * NF * THW + tile_px0(t)
                          + (long)s * sstr;
        #pragma unroll
        for (int i = 0; i < 8; ++i) {
            int f = f0 + i * 2;
            glds16(base + (long)f * THW + pl_off, (void*)&fbuf[buf][f][0]);
        }
    };
    auto stage_p = [&](int t) {
        const float* base = ps + (long)tile_b(t) * NP * THW + tile_px0(t);
        #pragma unroll
        for (int i = 0; i < 2; ++i) {
            int p = wv * 4 + i * 2;
            glds16(base + (long)p * THW + pl_off, (void*)&pbuf[p][0]);
        }
    };

    // ---- prologue: stage tile0 p + s0 (10 DMAs in flight)
    stage_p(0);
    stage_feats(0, 0, 0);
    asm volatile("s_waitcnt lgkmcnt(0)" ::: "memory");   // w1lds/tbl visible
    __builtin_amdgcn_s_barrier();

    // ---- hoist A fragments (w1*scale) and shift/w2 (per-lane)
    FragU afr[5];
    {
        const uint32_t abase = (uint32_t)(ln * 44 + hi * 4);
        #pragma unroll
        for (int k = 0; k < 5; ++k)
            afr[k].q = *((const uint4*)&w1lds[abase + k * 8]);
    }
    float sh[16], wo[16];
    #pragma unroll
    for (int r = 0; r < 16; ++r) {
        float2 t2 = tbl[(r & 3) + 8 * (r >> 2) + 4 * hi];
        sh[r] = t2.x;
        wo[r] = t2.y;
    }

    const int pxloc = wv * 32 + ln;

    FragU bp;
    auto consume = [&](int buf, FragU* pk) -> float {
        #pragma unroll
        for (int kb = 0; kb < 4; ++kb)
            #pragma unroll
            for (int r = 0; r < 4; ++r)
                pk[kb].u[r] = pk2(fbuf[buf][kb * 16 + hi * 8 + 2 * r][pxloc],
                                  fbuf[buf][kb * 16 + hi * 8 + 2 * r + 1][pxloc]);
        f32x16 acc;
        #pragma unroll
        for (int r = 0; r < 16; ++r) acc[r] = 0.f;
        acc = __builtin_amdgcn_mfma_f32_32x32x16_bf16(afr[4].v, bp.v,    acc, 0, 0, 0);
        acc = __builtin_amdgcn_mfma_f32_32x32x16_bf16(afr[0].v, pk[0].v, acc, 0, 0, 0);
        acc = __builtin_amdgcn_mfma_f32_32x32x16_bf16(afr[1].v, pk[1].v, acc, 0, 0, 0);
        acc = __builtin_amdgcn_mfma_f32_32x32x16_bf16(afr[2].v, pk[2].v, acc, 0, 0, 0);
        acc = __builtin_amdgcn_mfma_f32_32x32x16_bf16(afr[3].v, pk[3].v, acc, 0, 0, 0);
        float pp4[4] = {0.f, 0.f, 0.f, 0.f};
        #pragma unroll
        for (int r = 0; r < 16; ++r) {
            float h = fmaxf(acc[r] + sh[r], 0.f);
            pp4[r & 3] = fmaf(h, wo[r], pp4[r & 3]);
        }
        float part = (pp4[0] + pp4[1]) + (pp4[2] + pp4[3]);
        return part + __shfl_xor(part, 32);
    };

    for (int t = 0; t < TPB; ++t) {
        FragU pk0[4], pk1[4], pk2f[4], pk3[4];
        float lg0, lg1, lg2, lg3;

        // phase s=0: consume buf0 (p + s0 staged 1 phase ago); stage s1->buf1
        stage_feats(t, 1, 1);
        asm volatile("s_waitcnt vmcnt(8)" ::: "memory");
        __builtin_amdgcn_s_barrier();
        #pragma unroll
        for (int r = 0; r < 4; ++r)
            bp.u[r] = pk2(pbuf[hi * 8 + 2 * r][pxloc], pbuf[hi * 8 + 2 * r + 1][pxloc]);
        lg0 = consume(0, pk0);
        __builtin_amdgcn_s_barrier();

        // phase s=1: stage s2->buf0
        stage_feats(t, 2, 0);
        asm volatile("s_waitcnt vmcnt(8)" ::: "memory");
        __builtin_amdgcn_s_barrier();
        lg1 = consume(1, pk1);
        __builtin_amdgcn_s_barrier();

        // phase s=2: stage s3->buf1
        stage_feats(t, 3, 1);
        asm volatile("s_waitcnt vmcnt(8)" ::: "memory");
        __builtin_amdgcn_s_barrier();
        lg2 = consume(0, pk2f);
        __builtin_amdgcn_s_barrier();

        // phase s=3: stage next tile's p + s0 -> buf0 (10 DMAs), or drain at end
        if (t + 1 < TPB) {
            stage_p(t + 1);
            stage_feats(t + 1, 0, 0);
            asm volatile("s_waitcnt vmcnt(10)" ::: "memory");
        } else {
            asm volatile("s_waitcnt vmcnt(0)" ::: "memory");
        }
        __builtin_amdgcn_s_barrier();
        lg3 = consume(1, pk3);

        // ---- softmax + epilogue for tile t (b2 shift-invariant: skipped)
        const float m   = fmaxf(fmaxf(lg0, lg1), fmaxf(lg2, lg3));
        const float e0  = __expf(lg0 - m), e1 = __expf(lg1 - m);
        const float e2  = __expf(lg2 - m), e3 = __expf(lg3 - m);
        const float inv = 1.f / (e0 + e1 + e2 + e3);
        const float a0 = e0 * inv, a1 = e1 * inv, a2 = e2 * inv, a3 = e3 * inv;

        const int b   = tile_b(t);
        const int thw = tile_px0(t) + pxloc;

        float* ob = out + ((long)(b * NF + hi * 8)) * THW + thw;
        #pragma unroll
        for (int k = 0; k < 4; ++k)
            #pragma unroll
            for (int r = 0; r < 4; ++r) {
                float vlo = a0 * lo16(pk0[k].u[r]);
                float vhi = a0 * hi16(pk0[k].u[r]);
                vlo = fmaf(a1, lo16(pk1[k].u[r]), vlo);
                vhi = fmaf(a1, hi16(pk1[k].u[r]), vhi);
                vlo = fmaf(a2, lo16(pk2f[k].u[r]), vlo);
                vhi = fmaf(a2, hi16(pk2f[k].u[r]), vhi);
                vlo = fmaf(a3, lo16(pk3[k].u[r]), vlo);
                vhi = fmaf(a3, hi16(pk3[k].u[r]), vhi);
                ob[(long)(k * 16 + 2 * r)     * THW] = vlo;
                ob[(long)(k * 16 + 2 * r + 1) * THW] = vhi;
            }

        float* ab = out + (long)NB * NF * THW + ((long)(b * NS + hi * 2)) * THW + thw;
        ab[0]   = hi ? a2 : a0;
        ab[THW] = hi ? a3 : a1;

        __builtin_amdgcn_s_barrier();   // close phase s=3 (buf1 reuse at t+1 s=1)
    }
}

extern "C" void kernel_launch(void* const* d_in, const int* in_sizes, int n_in,
                              void* d_out, int out_size, void* d_ws, size_t ws_size,
                              hipStream_t stream) {
    const float* feats = (const float*)d_in[0];
    const float* ps    = (const float*)d_in[1];
    const float* w1    = (const float*)d_in[2];
    const float* gamma = (const float*)d_in[3];
    const float* beta  = (const float*)d_in[4];
    const float* mean  = (const float*)d_in[5];
    const float* var   = (const float*)d_in[6];
    const float* w2    = (const float*)d_in[7];
    float* out = (float*)d_out;

    dim3 grid(512), block(256);   // persistent: 512 blocks x 4 tiles x 128 px
    hipLaunchKernelGGL(gssm_kernel, grid, block, 0, stream,
                       feats, ps, w1, gamma, beta, mean, var, w2, out);
}